// Round 1
// baseline (396.745 us; speedup 1.0000x reference)
//
#include <hip/hip_runtime.h>

// LSTMSoftAttention on MI355X.
// Shapes: H=1024, N=2048, T=2048, B=16, all fp32.
// Single pass over enc (256 MiB) with unnormalized softmax accumulation
// (|score| <= sum|v| ~= 36, exp() cannot overflow fp32, no running max).
//
// v2 restructure:
//  - k_main: wave-independent rows (8 rows/wave, full 2048-col row per wave,
//    lane holds 8 float4 fragments). No __syncthreads in the main loop ->
//    no per-row vmcnt(0) drain; enc double-buffered in registers; cov/mask
//    prefetched for all 8 rows up front. One LDS combine at block end.
//  - k_final: fuses l_inv + context-finalize + attn/coverage-finalize
//    (every block recomputes the 16 l_inv values from the 4 KB l_part).
//
// Workspace (floats): dec_fea 32768 | p 32768 | l_part 1024 | (16 pad) |
//                     c_part 64*16*2048 = 2097152  -> ~8.7 MB.

#define HH 1024
#define NNF 2048
#define TTT 2048
#define BB 16
#define NCHUNK 64           // blocks along T; 32 rows per block

#define WS_DECFEA 0
#define WS_P      (BB * NNF)                 // 32768
#define WS_LPART  (WS_P + TTT * BB)          // 65536
#define WS_LINV   (WS_LPART + NCHUNK * BB)   // 66560 (kept for layout compat)
#define WS_CPART  (WS_LINV + 16)             // 66576 (16B aligned)

__device__ __forceinline__ float tanh_fast(float x) {
    // tanh(x) = 1 - 2/(exp(2x)+1); saturates correctly at +-inf.
    float e = __expf(2.0f * x);
    return 1.0f - 2.0f * __builtin_amdgcn_rcpf(e + 1.0f);
}

__global__ __launch_bounds__(256) void k_decfea(const float* __restrict__ dec,
                                                const float* __restrict__ Wd,
                                                const float* __restrict__ bd,
                                                float* __restrict__ dec_fea) {
    // one wave per output element (b, n)
    int gw   = (blockIdx.x * 256 + threadIdx.x) >> 6;
    int lane = threadIdx.x & 63;
    int b = gw >> 11;        // / 2048
    int n = gw & (NNF - 1);
    const float* dr = dec + b * HH;
    const float* wr = Wd + (size_t)n * HH;
    float acc = 0.0f;
#pragma unroll
    for (int it = 0; it < 4; ++it) {
        int h = it * 256 + lane * 4;
        float4 a = *(const float4*)(dr + h);
        float4 w = *(const float4*)(wr + h);
        acc = fmaf(a.x, w.x, acc);
        acc = fmaf(a.y, w.y, acc);
        acc = fmaf(a.z, w.z, acc);
        acc = fmaf(a.w, w.w, acc);
    }
#pragma unroll
    for (int off = 32; off; off >>= 1) acc += __shfl_down(acc, off, 64);
    if (lane == 0) dec_fea[b * NNF + n] = acc + bd[n];
}

// ---- k_main helpers (all arrays indexed with compile-time constants only) ----

__device__ __forceinline__ void load_row8(const float* __restrict__ p, int nb,
                                          float4* dst) {
#pragma unroll
    for (int j = 0; j < 8; ++j) dst[j] = *(const float4*)(p + j * 256 + nb);
}

__device__ __forceinline__ float score8(const float4* e, const float4* d,
                                        const float4* w, const float4* vv,
                                        float cv) {
    float s = 0.0f;
#pragma unroll
    for (int j = 0; j < 8; ++j) {
        float a;
        a = fmaf(cv, w[j].x, e[j].x + d[j].x); s = fmaf(tanh_fast(a), vv[j].x, s);
        a = fmaf(cv, w[j].y, e[j].y + d[j].y); s = fmaf(tanh_fast(a), vv[j].y, s);
        a = fmaf(cv, w[j].z, e[j].z + d[j].z); s = fmaf(tanh_fast(a), vv[j].z, s);
        a = fmaf(cv, w[j].w, e[j].w + d[j].w); s = fmaf(tanh_fast(a), vv[j].w, s);
    }
    return s;
}

__device__ __forceinline__ void acc8(float4* acc, const float4* e, float p) {
#pragma unroll
    for (int j = 0; j < 8; ++j) {
        acc[j].x = fmaf(p, e[j].x, acc[j].x);
        acc[j].y = fmaf(p, e[j].y, acc[j].y);
        acc[j].z = fmaf(p, e[j].z, acc[j].z);
        acc[j].w = fmaf(p, e[j].w, acc[j].w);
    }
}

__global__ __launch_bounds__(256) void k_main(const float* __restrict__ enc,
                                              const int* __restrict__ mask,
                                              const float* __restrict__ cov,
                                              const float* __restrict__ wc,
                                              const float* __restrict__ v,
                                              float* __restrict__ ws) {
    const int b     = blockIdx.y;
    const int chunk = blockIdx.x;
    const int tid   = threadIdx.x;
    const int lane  = tid & 63;
    const int wid   = tid >> 6;
    const int t0    = chunk * 32 + wid * 8;   // this wave's first row
    const int nb    = lane * 4;               // per-lane col offset in 256-chunk

    const float* dec_fea = ws + WS_DECFEA;
    float* ws_p     = ws + WS_P;
    float* ws_lpart = ws + WS_LPART;
    float* cpart    = ws + WS_CPART;

    // constant per-lane fragments: dec_fea, wc, v (n = j*256 + lane*4)
    float4 dfr[8], wcr[8], vfr[8];
#pragma unroll
    for (int j = 0; j < 8; ++j) {
        dfr[j] = *(const float4*)(dec_fea + b * NNF + j * 256 + nb);
        wcr[j] = *(const float4*)(wc + j * 256 + nb);
        vfr[j] = *(const float4*)(v + j * 256 + nb);
    }

    // prefetch cov/mask for all 8 rows (broadcast scalar loads, all independent)
    float cv_r[8];
    int mkbits = 0;
#pragma unroll
    for (int r = 0; r < 8; ++r) {
        cv_r[r] = cov[(t0 + r) * BB + b];
        mkbits |= (mask[(t0 + r) * BB + b] != 0) << r;
    }

    const float* base = enc + ((size_t)t0 * BB + b) * NNF;
    const size_t rstride = (size_t)BB * NNF;

    float4 bufA[8], bufB[8];
    load_row8(base, nb, bufA);

    float4 acc[8];
#pragma unroll
    for (int j = 0; j < 8; ++j) acc[j] = make_float4(0.f, 0.f, 0.f, 0.f);
    float l_loc = 0.0f;

#pragma unroll
    for (int rr = 0; rr < 4; ++rr) {
        const int r0 = 2 * rr, r1 = 2 * rr + 1;

        // row r0 lives in bufA; prefetch row r1 into bufB
        load_row8(base + (size_t)r1 * rstride, nb, bufB);
        {
            float s = score8(bufA, dfr, wcr, vfr, cv_r[r0]);
#pragma unroll
            for (int off = 1; off < 64; off <<= 1) s += __shfl_xor(s, off, 64);
            const float p = ((mkbits >> r0) & 1) ? 0.0f : __expf(s);
            l_loc += p;
            if (lane == 0) ws_p[(t0 + r0) * BB + b] = p;
            acc8(acc, bufA, p);
        }

        // row r1 lives in bufB; prefetch row r1+1 into bufA (except last)
        if (rr < 3) load_row8(base + (size_t)(r1 + 1) * rstride, nb, bufA);
        {
            float s = score8(bufB, dfr, wcr, vfr, cv_r[r1]);
#pragma unroll
            for (int off = 1; off < 64; off <<= 1) s += __shfl_xor(s, off, 64);
            const float p = ((mkbits >> r1) & 1) ? 0.0f : __expf(s);
            l_loc += p;
            if (lane == 0) ws_p[(t0 + r1) * BB + b] = p;
            acc8(acc, bufB, p);
        }
    }

    // combine the 4 waves' context partials + l partials (single barrier)
    __shared__ float4 smc[4][512];   // 32 KB
    __shared__ float  sml[4];
#pragma unroll
    for (int j = 0; j < 8; ++j) smc[wid][j * 64 + lane] = acc[j];
    if (lane == 0) sml[wid] = l_loc;
    __syncthreads();
    if (tid == 0) ws_lpart[chunk * BB + b] = (sml[0] + sml[1]) + (sml[2] + sml[3]);
    float* cp = cpart + (size_t)(chunk * BB + b) * NNF;
#pragma unroll
    for (int i = tid; i < 512; i += 256) {
        float4 s0 = smc[0][i], s1 = smc[1][i], s2 = smc[2][i], s3 = smc[3][i];
        float4 o;
        o.x = (s0.x + s1.x) + (s2.x + s3.x);
        o.y = (s0.y + s1.y) + (s2.y + s3.y);
        o.z = (s0.z + s1.z) + (s2.z + s3.z);
        o.w = (s0.w + s1.w) + (s2.w + s3.w);
        const int j = i >> 6, l = i & 63;
        *(float4*)(cp + j * 256 + l * 4) = o;
    }
}

// Fused: l_inv + context finalize + attn/coverage finalize.
// Blocks [0,32): context (B*N/4 float4s). Blocks [32,160): attn+cov (T*B).
__global__ __launch_bounds__(256) void k_final(const float* __restrict__ ws,
                                               const float* __restrict__ cov,
                                               float* __restrict__ out_c,
                                               float* __restrict__ out_attn,
                                               float* __restrict__ out_cov) {
    const int tid = threadIdx.x;
    const int bx  = blockIdx.x;

    // every block recomputes l_inv[0..15] from the 1024-float l_part
    __shared__ float sm[16][16];
    __shared__ float linv_s[16];
    const float* lp = ws + WS_LPART;
    // lp[tid + 256k] has b = tid & 15 for all k
    float s4 = (lp[tid] + lp[tid + 256]) + (lp[tid + 512] + lp[tid + 768]);
    sm[tid >> 4][tid & 15] = s4;
    __syncthreads();
    if (tid < 16) {
        float t = 0.0f;
#pragma unroll
        for (int k = 0; k < 16; ++k) t += sm[k][tid];
        linv_s[tid] = 1.0f / t;
    }
    __syncthreads();

    if (bx < 32) {
        // context: sum 64 chunk partials, scale by l_inv
        const int idx4 = (bx * 256 + tid) * 4;
        const int b = idx4 >> 11;
        const int n = idx4 & (NNF - 1);
        const float* cp = ws + WS_CPART + (size_t)b * NNF + n;
        float4 s = make_float4(0.f, 0.f, 0.f, 0.f);
#pragma unroll 8
        for (int j = 0; j < NCHUNK; ++j) {
            float4 a = *(const float4*)(cp + (size_t)j * BB * NNF);
            s.x += a.x; s.y += a.y; s.z += a.z; s.w += a.w;
        }
        const float li = linv_s[b];
        s.x *= li; s.y *= li; s.z *= li; s.w *= li;
        *(float4*)(out_c + idx4) = s;
    } else {
        const int idx = (bx - 32) * 256 + tid;  // t*B + b
        const int b = idx & (BB - 1);
        const float a = ws[WS_P + idx] * linv_s[b];
        out_attn[idx] = a;
        out_cov[idx] = cov[idx] + a;
    }
}

extern "C" void kernel_launch(void* const* d_in, const int* in_sizes, int n_in,
                              void* d_out, int out_size, void* d_ws, size_t ws_size,
                              hipStream_t stream) {
    const float* dec  = (const float*)d_in[0];
    const float* enc  = (const float*)d_in[1];
    const int*   mask = (const int*)d_in[2];
    const float* cov  = (const float*)d_in[3];
    const float* Wd   = (const float*)d_in[4];
    const float* bd   = (const float*)d_in[5];
    const float* wc   = (const float*)d_in[6];
    const float* v    = (const float*)d_in[7];
    float* ws  = (float*)d_ws;
    float* out = (float*)d_out;

    float* out_c    = out;                 // (B, N)   32768
    float* out_attn = out + BB * NNF;      // (T, B)   32768
    float* out_cov  = out_attn + TTT * BB; // (T, B)   32768

    // 1. dec_fea: B*N waves = 32768 waves -> 8192 blocks of 256
    k_decfea<<<8192, 256, 0, stream>>>(dec, Wd, bd, ws + WS_DECFEA);

    // 2. main fused pass over enc: barrier-free wave-per-row
    dim3 g2(NCHUNK, BB);
    k_main<<<g2, 256, 0, stream>>>(enc, mask, cov, wc, v, ws);

    // 3. fused finalize (l_inv + context + attn/coverage)
    k_final<<<160, 256, 0, stream>>>(ws, cov, out_c, out_attn, out_cov);
}